// Round 11
// baseline (68452.118 us; speedup 1.0000x reference)
//
#include <hip/hip_runtime.h>
#include <hip/hip_bf16.h>
#include <math.h>

typedef unsigned int u32;
typedef unsigned short u16;

// ---------- bf16 helpers ----------
__device__ __forceinline__ float bfbits(u32 hi) { union { u32 u; float f; } v; v.u = hi; return v.f; }
__device__ __forceinline__ float lo16(u32 p) { return bfbits(p << 16); }
__device__ __forceinline__ float hi16(u32 p) { return bfbits(p & 0xffff0000u); }
__device__ __forceinline__ float b2f(u16 x) { return bfbits(((u32)x) << 16); }
__device__ __forceinline__ u16 f2b(float f) {
    union { float f; u32 u; } v; v.f = f;
    u32 u = v.u;
    u32 r = (u + 0x7fffu + ((u >> 16) & 1u)) >> 16;  // RNE
    return (u16)r;
}
__device__ __forceinline__ float cvtf(float x) { return x; }
__device__ __forceinline__ float cvtf(u16 x) { return b2f(x); }
__device__ __forceinline__ void storef(float* p, float v) { *p = v; }
__device__ __forceinline__ void storef(u16* p, float v) { *p = f2b(v); }
__device__ __forceinline__ float sigf(float x) { return 1.f / (1.f + expf(-x)); }
// dot of one uint4 (8 packed bf16) against 8 floats at p (LDS)
__device__ __forceinline__ float dotq(uint4 q, const float* p) {
    float4 a = *(const float4*)p;
    float4 b = *(const float4*)(p + 4);
    return lo16(q.x) * a.x + hi16(q.x) * a.y + lo16(q.y) * a.z + hi16(q.y) * a.w
         + lo16(q.z) * b.x + hi16(q.z) * b.y + lo16(q.w) * b.z + hi16(q.w) * b.w;
}
// dot against 8 floats held in two float4 registers
__device__ __forceinline__ float dotq2(uint4 q, float4 a, float4 b) {
    return lo16(q.x) * a.x + hi16(q.x) * a.y + lo16(q.y) * a.z + hi16(q.y) * a.w
         + lo16(q.z) * b.x + hi16(q.z) * b.y + lo16(q.w) * b.z + hi16(q.w) * b.w;
}
// 8-lane group reduce (lanes differing in bits 0..2)
__device__ __forceinline__ float red8(float a) {
    a += __shfl_xor(a, 1);
    a += __shfl_xor(a, 2);
    a += __shfl_xor(a, 4);
    return a;
}

// ---------- dtype-world detector (proven) ----------
__global__ void k_detect(const void* __restrict__ emb, int* __restrict__ flag) {
    __shared__ int s;
    if (threadIdx.x == 0) s = 0;
    __syncthreads();
    const u16* p = (const u16*)emb;
    int bad = 0;
    for (int i = threadIdx.x; i < 8192; i += 256) {
        float v = b2f(p[i]);
        if (!(fabsf(v) < 1e4f)) bad = 1;
    }
    if (bad) s = 1;
    __syncthreads();
    if (threadIdx.x == 0) *flag = s;
}

// ---------- weight canonicalizer ----------
__global__ void k_conv(const void* __restrict__ src, u16* __restrict__ dst, int n,
                       const int* __restrict__ flag) {
    int i = blockIdx.x * 256 + threadIdx.x;
    if (i >= n) return;
    if (*flag) dst[i] = f2b(((const float*)src)[i]);
    else       dst[i] = ((const u16*)src)[i];
}

// ---------- Watt transpose ----------
__global__ void k_wattT(const void* __restrict__ src, u16* __restrict__ dst,
                        const int* __restrict__ flag) {
    int c = blockIdx.x;   // 0..511
    int r = threadIdx.x;  // 0..255
    u16 v;
    if (*flag) v = f2b(((const float*)src)[(size_t)r * 512 + c]);
    else       v = ((const u16*)src)[(size_t)r * 512 + c];
    dst[(size_t)c * 256 + r] = v;
}

// ---------- embedding gather -> internal bf16 ----------
__global__ void k_embed(const int* __restrict__ tok, const void* __restrict__ emb,
                        u16* __restrict__ out, const int* __restrict__ flag) {
    int row = blockIdx.x;
    int e = threadIdx.x;
    int v = tok[row];
    u16 r;
    if (*flag) r = f2b(((const float*)emb)[(size_t)v * 256 + e]);
    else       r = ((const u16*)emb)[(size_t)v * 256 + e];
    out[(size_t)row * 256 + e] = r;
}

// ---------- generic GEMM: C[m][n] = sum_k A[m][k]*B[n][k] (+bias[n]) ----------
template <typename TA, typename TC>
__global__ __launch_bounds__(256) void k_gemm_nt(
    const TA* __restrict__ A, int lda,
    const u16* __restrict__ B, int ldb,
    const u16* __restrict__ bias,
    TC* __restrict__ C, int ldc,
    int M, int N, int K) {
    __shared__ float As[32][68];
    __shared__ float Bs[32][68];
    const int bm = blockIdx.y * 64, bn = blockIdx.x * 64;
    const int tid = threadIdx.x;
    const int tm = (tid & 15) * 4, tn = (tid >> 4) * 4;
    float acc[4][4] = {};
    const int ml = tid >> 2, kl = (tid & 3) * 8;
    for (int k0 = 0; k0 < K; k0 += 32) {
        {
            float v[8];
            if (bm + ml < M) {
                const TA* ap = A + (size_t)(bm + ml) * lda + (k0 + kl);
#pragma unroll
                for (int i = 0; i < 8; i++) v[i] = cvtf(ap[i]);
            } else {
#pragma unroll
                for (int i = 0; i < 8; i++) v[i] = 0.f;
            }
#pragma unroll
            for (int i = 0; i < 8; i++) As[kl + i][ml] = v[i];
        }
        {
            float v[8];
            if (bn + ml < N) {
                const u16* bp = B + (size_t)(bn + ml) * ldb + (k0 + kl);
#pragma unroll
                for (int i = 0; i < 8; i++) v[i] = b2f(bp[i]);
            } else {
#pragma unroll
                for (int i = 0; i < 8; i++) v[i] = 0.f;
            }
#pragma unroll
            for (int i = 0; i < 8; i++) Bs[kl + i][ml] = v[i];
        }
        __syncthreads();
#pragma unroll
        for (int k = 0; k < 32; k++) {
            float4 av = *(const float4*)&As[k][tm];
            float4 bv = *(const float4*)&Bs[k][tn];
            acc[0][0] += av.x * bv.x; acc[0][1] += av.x * bv.y; acc[0][2] += av.x * bv.z; acc[0][3] += av.x * bv.w;
            acc[1][0] += av.y * bv.x; acc[1][1] += av.y * bv.y; acc[1][2] += av.y * bv.z; acc[1][3] += av.y * bv.w;
            acc[2][0] += av.z * bv.x; acc[2][1] += av.z * bv.y; acc[2][2] += av.z * bv.z; acc[2][3] += av.z * bv.w;
            acc[3][0] += av.w * bv.x; acc[3][1] += av.w * bv.y; acc[3][2] += av.w * bv.z; acc[3][3] += av.w * bv.w;
        }
        __syncthreads();
    }
#pragma unroll
    for (int i = 0; i < 4; i++) {
        int m = bm + tm + i;
        if (m >= M) continue;
#pragma unroll
        for (int j = 0; j < 4; j++) {
            int n = bn + tn + j;
            float v = acc[i][j];
            if (bias) v += b2f(bias[n]);
            storef(&C[(size_t)m * ldc + n], v);
        }
    }
}

// ---------- persistent encoder (r9, proven): 64 blocks x 512 thr, 512 steps ----------
__global__ __launch_bounds__(512) void k_enc_persist(
    const u16* __restrict__ Xf, const u16* __restrict__ Xb,
    const u16* __restrict__ Whh_f, const u16* __restrict__ Whh_b,
    u16* __restrict__ enc, float* __restrict__ hFB) {
    const int d = blockIdx.x >> 5, b = blockIdx.x & 31;
    const int t = threadIdx.x;
    const u16* W = d ? Whh_b : Whh_f;
    const uint4* wr0 = (const uint4*)(W + (size_t)t * 256);
    const uint4* wr1 = (const uint4*)(W + (size_t)(t + 512) * 256);
    __shared__ float hs[256];
    __shared__ float af[256], ao[256];
    float c = 0.f;
    if (t < 256) hs[t] = 0.f;
    __syncthreads();
    const u16* Xd = d ? Xb : Xf;
    for (int step = 0; step < 512; step++) {
        const int pos = d ? (511 - step) : step;
        const u16* xp = Xd + ((size_t)pos * 32 + b) * 1024;
        float a0 = b2f(xp[t]), a1 = b2f(xp[t + 512]);
#pragma unroll 8
        for (int i = 0; i < 32; i++) {
            a0 += dotq(wr0[i], &hs[i * 8]);
            a1 += dotq(wr1[i], &hs[i * 8]);
        }
        if (t >= 256) { af[t - 256] = a0; ao[t - 256] = a1; }
        __syncthreads();
        if (t < 256) {
            float ig = sigf(a0), gg = tanhf(a1);
            float fg = sigf(af[t]), og = sigf(ao[t]);
            c = fg * c + ig * gg;
            float h = og * tanhf(c);
            hs[t] = h;
            enc[((size_t)b * 512 + pos) * 512 + (size_t)d * 256 + t] = f2b(h);
        }
        __syncthreads();
    }
    if (t < 256) hFB[(size_t)b * 512 + (size_t)d * 256 + t] = hs[t];
}

// ---------- persistent decoder v2: 32 blocks (batch) x 512 thr, 127 steps ----------
// No cross-block sync. 8-lane-per-row coalesced weight reads; e+softmax+ctx fused
// into ONE enc pass (online accumulation) -> no encT, per-XCD L2 footprint ~3.7MB.
__global__ __launch_bounds__(512) void k_dec_persist(
    const u16* __restrict__ Ypart,
    const u16* __restrict__ Whh_d, const u16* __restrict__ Wih_d,
    const u16* __restrict__ WattT, const u16* __restrict__ Wcomb,
    const u16* __restrict__ enc,
    const float* __restrict__ ht0, const float* __restrict__ ct0,
    float* __restrict__ hid) {
    const int b = blockIdx.x;
    const int j = threadIdx.x;
    const int q = j & 7, r8i = j >> 3;   // 8 lanes per row
    const int wv = j >> 6, ln = j & 63;  // wave / lane
    __shared__ float hs[256], os[256];
    __shared__ float gall[1024];
    __shared__ float g[512];
    __shared__ float pctxw[8][512];
    __shared__ float hc[768];
    __shared__ float redw[8];
    float c = 0.f;
    if (j < 256) {
        hs[j] = ht0[(size_t)b * 256 + j];
        c = ct0[(size_t)b * 256 + j];
        os[j] = 0.f;
    }
    __syncthreads();
    const uint4* encb = (const uint4*)(enc + (size_t)b * 512 * 512);
    for (int s = 0; s < 127; s++) {
        const u16* yp = Ypart + ((size_t)s * 32 + b) * 1024;
        // ---- A: all 1024 gate rows, 8 lanes/row ----
#pragma unroll
        for (int it = 0; it < 16; it++) {
            int row = it * 64 + r8i;
            const uint4* wh = (const uint4*)(Whh_d + (size_t)row * 256);
            const uint4* wo = (const uint4*)(Wih_d + (size_t)row * 512 + 256);
            float a = 0.f;
#pragma unroll
            for (int i = 0; i < 4; i++) {
                int u = q + 8 * i;
                a += dotq(wh[u], &hs[u * 8]);
                a += dotq(wo[u], &os[u * 8]);
            }
            a = red8(a);
            if (q == 0) gall[row] = a + b2f(yp[row]);
        }
        __syncthreads();
        // ---- h/c update (i,f,g,o rows 0/256/512/768) ----
        if (j < 256) {
            float ig = sigf(gall[j]), fg = sigf(gall[256 + j]);
            float gg = tanhf(gall[512 + j]), og = sigf(gall[768 + j]);
            c = fg * c + ig * gg;
            hs[j] = og * tanhf(c);
        }
        __syncthreads();
        // ---- B: g = WattT . h (512 rows) ----
#pragma unroll
        for (int it = 0; it < 8; it++) {
            int row = it * 64 + r8i;
            const uint4* wt = (const uint4*)(WattT + (size_t)row * 256);
            float a = 0.f;
#pragma unroll
            for (int i = 0; i < 4; i++) {
                int u = q + 8 * i;
                a += dotq(wt[u], &hs[u * 8]);
            }
            a = red8(a);
            if (q == 0) g[row] = a;
        }
        __syncthreads();
        // ---- C: fused e -> exp -> ctx accumulation, ONE pass over enc ----
        {
            float4 ga = *(const float4*)&g[ln * 8];
            float4 gb = *(const float4*)&g[ln * 8 + 4];
            float a0 = 0, a1 = 0, a2 = 0, a3 = 0, a4 = 0, a5 = 0, a6 = 0, a7 = 0;
            float suma = 0.f;
#pragma unroll 2
            for (int rr = 0; rr < 64; rr++) {
                int srow = wv * 64 + rr;
                uint4 qd = encb[(size_t)srow * 64 + ln];
                float e = dotq2(qd, ga, gb);
                e += __shfl_xor(e, 1); e += __shfl_xor(e, 2); e += __shfl_xor(e, 4);
                e += __shfl_xor(e, 8); e += __shfl_xor(e, 16); e += __shfl_xor(e, 32);
                float w = expf(e);
                suma += w;
                a0 += w * lo16(qd.x); a1 += w * hi16(qd.x);
                a2 += w * lo16(qd.y); a3 += w * hi16(qd.y);
                a4 += w * lo16(qd.z); a5 += w * hi16(qd.z);
                a6 += w * lo16(qd.w); a7 += w * hi16(qd.w);
            }
            float* pw = &pctxw[wv][ln * 8];
            pw[0] = a0; pw[1] = a1; pw[2] = a2; pw[3] = a3;
            pw[4] = a4; pw[5] = a5; pw[6] = a6; pw[7] = a7;
            if (ln == 0) redw[wv] = suma;
        }
        __syncthreads();
        // ---- reduce ctx over waves, build [h;ctx] ----
        {
            float cxv = 0.f;
#pragma unroll
            for (int w = 0; w < 8; w++) cxv += pctxw[w][j];
            float inv = 1.f / (redw[0] + redw[1] + redw[2] + redw[3] +
                               redw[4] + redw[5] + redw[6] + redw[7]);
            hc[256 + j] = cxv * inv;
            if (j < 256) hc[j] = hs[j];
        }
        __syncthreads();
        // ---- E: o_t = tanh(Wcomb [h;ctx]) (256 rows, 8 lanes/row) ----
#pragma unroll
        for (int it = 0; it < 4; it++) {
            int row = it * 64 + r8i;
            const uint4* wc = (const uint4*)(Wcomb + (size_t)row * 768);
            float a = 0.f;
#pragma unroll
            for (int i = 0; i < 12; i++) {
                int u = q + 8 * i;
                a += dotq(wc[u], &hc[u * 8]);
            }
            a = red8(a);
            if (q == 0) {
                float o = tanhf(a);
                os[row] = o;
                hid[((size_t)s * 32 + b) * 256 + row] = o;
            }
        }
        __syncthreads();
    }
}

// ---------- logit at target index ----------
__global__ __launch_bounds__(256) void k_lidx(
    const int* __restrict__ target, const float* __restrict__ hid,
    const void* __restrict__ WvocV, float* __restrict__ lidx,
    const int* __restrict__ flag) {
    int p = blockIdx.x * 4 + (threadIdx.x >> 6);
    if (p >= 127 * 32) return;
    int lane = threadIdx.x & 63;
    int t = p >> 5, b = p & 31;
    int idx = target[(t + 1) * 32 + b];
    const float* h = hid + (size_t)p * 256;
    const bool f32w = (*flag != 0);
    float a = 0.f;
#pragma unroll
    for (int i = 0; i < 4; i++) {
        int k = lane * 4 + i;
        float wv = f32w ? ((const float*)WvocV)[(size_t)idx * 256 + k]
                        : b2f(((const u16*)WvocV)[(size_t)idx * 256 + k]);
        a += h[k] * wv;
    }
    for (int off = 32; off; off >>= 1) a += __shfl_down(a, off);
    if (lane == 0) lidx[p] = a;
}

// ---------- fused vocab GEMM + sum(exp(logit)) ----------
__global__ __launch_bounds__(256) void k_sumexp(
    const float* __restrict__ hid, const void* __restrict__ WvocV,
    float* __restrict__ psum, const int* __restrict__ flag) {
    const int t = blockIdx.y;
    const int cb = blockIdx.x * 128;
    const int tid = threadIdx.x;
    const bool f32w = (*flag != 0);
    __shared__ float Hsh[32][260];
    __shared__ float Wsh[32][132];
    __shared__ float red[32][33];
    {
        int r = tid >> 3, kb = (tid & 7) * 32;
        const float4* hp4 = (const float4*)(hid + ((size_t)t * 32 + r) * 256 + kb);
        float4* dst = (float4*)&Hsh[r][kb];
#pragma unroll
        for (int i = 0; i < 8; i++) dst[i] = hp4[i];
    }
    const int rt = tid >> 5, ct = tid & 31;
    float acc[4][4] = {};
    for (int kc = 0; kc < 8; kc++) {
        __syncthreads();
        {
            int c = tid >> 1, half = tid & 1;
            int k0 = half * 16;
            float w[16];
            if (f32w) {
                const float4* wf = (const float4*)((const float*)WvocV + (size_t)(cb + c) * 256 + kc * 32 + half * 16);
                float4 a0 = wf[0], a1 = wf[1], a2 = wf[2], a3 = wf[3];
                w[0] = a0.x; w[1] = a0.y; w[2] = a0.z; w[3] = a0.w;
                w[4] = a1.x; w[5] = a1.y; w[6] = a1.z; w[7] = a1.w;
                w[8] = a2.x; w[9] = a2.y; w[10] = a2.z; w[11] = a2.w;
                w[12] = a3.x; w[13] = a3.y; w[14] = a3.z; w[15] = a3.w;
            } else {
                const uint4* w4 = (const uint4*)((const u16*)WvocV + (size_t)(cb + c) * 256 + kc * 32 + half * 16);
                uint4 q0 = w4[0], q1 = w4[1];
                w[0] = lo16(q0.x); w[1] = hi16(q0.x); w[2] = lo16(q0.y); w[3] = hi16(q0.y);
                w[4] = lo16(q0.z); w[5] = hi16(q0.z); w[6] = lo16(q0.w); w[7] = hi16(q0.w);
                w[8] = lo16(q1.x); w[9] = hi16(q1.x); w[10] = lo16(q1.y); w[11] = hi16(q1.y);
                w[12] = lo16(q1.z); w[13] = hi16(q1.z); w[14] = lo16(q1.w); w[15] = hi16(q1.w);
            }
#pragma unroll
            for (int i = 0; i < 16; i++) Wsh[k0 + i][c] = w[i];
        }
        __syncthreads();
#pragma unroll
        for (int k = 0; k < 32; k++) {
            float4 bv = *(const float4*)&Wsh[k][ct * 4];
            float a0 = Hsh[rt * 4 + 0][kc * 32 + k];
            float a1 = Hsh[rt * 4 + 1][kc * 32 + k];
            float a2 = Hsh[rt * 4 + 2][kc * 32 + k];
            float a3 = Hsh[rt * 4 + 3][kc * 32 + k];
            acc[0][0] += a0 * bv.x; acc[0][1] += a0 * bv.y; acc[0][2] += a0 * bv.z; acc[0][3] += a0 * bv.w;
            acc[1][0] += a1 * bv.x; acc[1][1] += a1 * bv.y; acc[1][2] += a1 * bv.z; acc[1][3] += a1 * bv.w;
            acc[2][0] += a2 * bv.x; acc[2][1] += a2 * bv.y; acc[2][2] += a2 * bv.z; acc[2][3] += a2 * bv.w;
            acc[3][0] += a3 * bv.x; acc[3][1] += a3 * bv.y; acc[3][2] += a3 * bv.z; acc[3][3] += a3 * bv.w;
        }
    }
#pragma unroll
    for (int i = 0; i < 4; i++) {
        float s = expf(acc[i][0]) + expf(acc[i][1]) + expf(acc[i][2]) + expf(acc[i][3]);
        red[rt * 4 + i][ct] = s;
    }
    __syncthreads();
    if (tid < 32) {
        float s = 0.f;
#pragma unroll 8
        for (int c = 0; c < 32; c++) s += red[tid][c];
        atomicAdd(&psum[(size_t)t * 32 + tid], s);
    }
}

// ---------- final scores ----------
__global__ void k_scores(const int* __restrict__ target, const float* __restrict__ lidx,
                         const float* __restrict__ psum, void* __restrict__ outv,
                         const int* __restrict__ flag) {
    int b = threadIdx.x;
    if (b >= 32) return;
    float acc = 0.f;
    for (int t = 0; t < 127; t++) {
        int idx = target[(t + 1) * 32 + b];
        if (idx != 0) {
            int row = t * 32 + b;
            acc += lidx[row] - logf(psum[row]);
        }
    }
    if (*flag) ((float*)outv)[b] = acc;
    else       ((u16*)outv)[b] = f2b(acc);
}

extern "C" void kernel_launch(void* const* d_in, const int* in_sizes, int n_in,
                              void* d_out, int out_size, void* d_ws, size_t ws_size,
                              hipStream_t stream) {
    const int* source = (const int*)d_in[0];
    const int* target = (const int*)d_in[1];
    const void* src_emb = d_in[2];
    const void* tgt_emb = d_in[3];
    const void* Wih_f = d_in[4];
    const void* Whh_f = d_in[5];
    const void* b_f = d_in[6];
    const void* Wih_b = d_in[7];
    const void* Whh_b = d_in[8];
    const void* b_b = d_in[9];
    const void* Wih_d = d_in[10];
    const void* Whh_d = d_in[11];
    const void* b_d = d_in[12];
    const void* Wh = d_in[13];
    const void* Wc = d_in[14];
    const void* Watt = d_in[15];
    const void* Wcomb = d_in[16];
    const void* Wvoc = d_in[17];

    // ---- workspace layout: [flag pad][f32 buffers][u16 buffers] ----
    int* flag = (int*)d_ws;
    float* fw = (float*)d_ws;
    size_t off = 64;
    float* hid = fw + off;    off += (size_t)127 * 32 * 256;
    float* hFB = fw + off;    off += (size_t)32 * 512;
    float* ht0 = fw + off;    off += (size_t)32 * 256;
    float* ct0 = fw + off;    off += (size_t)32 * 256;
    float* lidx = fw + off;   off += 4096;
    float* psum = fw + off;   off += 4096;
    u16* ub = (u16*)(fw + off);
    size_t uo = 0;
    u16* X = ub + uo;       uo += (size_t)512 * 32 * 256;
    u16* Yemb = ub + uo;    uo += (size_t)127 * 32 * 256;
    u16* Xf = ub + uo;      uo += (size_t)512 * 32 * 1024;
    u16* Xb = ub + uo;      uo += (size_t)512 * 32 * 1024;
    u16* Ypart = ub + uo;   uo += (size_t)127 * 32 * 1024;
    u16* enc_p = ub + uo;   uo += (size_t)32 * 512 * 512;
    u16* WattT = ub + uo;   uo += 131072;
    u16* cWih_f = ub + uo;  uo += 262144;
    u16* cWhh_f = ub + uo;  uo += 262144;
    u16* cb_f = ub + uo;    uo += 1024;
    u16* cWih_b = ub + uo;  uo += 262144;
    u16* cWhh_b = ub + uo;  uo += 262144;
    u16* cb_b = ub + uo;    uo += 1024;
    u16* cWih_d = ub + uo;  uo += 524288;
    u16* cWhh_d = ub + uo;  uo += 262144;
    u16* cb_d = ub + uo;    uo += 1024;
    u16* cWh = ub + uo;     uo += 131072;
    u16* cWc = ub + uo;     uo += 131072;
    u16* cWcomb = ub + uo;  uo += 196608;
    size_t needed = off * 4 + uo * 2;
    if (ws_size < needed) return;

    // 0. detect dtype world, canonicalize weights
    k_detect<<<1, 256, 0, stream>>>(src_emb, flag);
    auto conv = [&](const void* s, u16* d, int n) {
        k_conv<<<(n + 255) / 256, 256, 0, stream>>>(s, d, n, flag);
    };
    conv(Wih_f, cWih_f, 262144);  conv(Whh_f, cWhh_f, 262144);  conv(b_f, cb_f, 1024);
    conv(Wih_b, cWih_b, 262144);  conv(Whh_b, cWhh_b, 262144);  conv(b_b, cb_b, 1024);
    conv(Wih_d, cWih_d, 524288);  conv(Whh_d, cWhh_d, 262144);  conv(b_d, cb_d, 1024);
    conv(Wh, cWh, 131072);        conv(Wc, cWc, 131072);
    conv(Wcomb, cWcomb, 196608);
    k_wattT<<<512, 256, 0, stream>>>(Watt, WattT, flag);

    // 1. embed source
    k_embed<<<512 * 32, 256, 0, stream>>>(source, src_emb, X, flag);
    // 2. x-part gate preactivations, both directions (bf16 out)
    k_gemm_nt<u16, u16><<<dim3(16, 256), 256, 0, stream>>>(X, 256, cWih_f, 256, cb_f, Xf, 1024, 16384, 1024, 256);
    k_gemm_nt<u16, u16><<<dim3(16, 256), 256, 0, stream>>>(X, 256, cWih_b, 256, cb_b, Xb, 1024, 16384, 1024, 256);
    // 3. persistent encoder
    k_enc_persist<<<64, 512, 0, stream>>>(Xf, Xb, cWhh_f, cWhh_b, enc_p, hFB);
    // 4. initial decoder state
    k_gemm_nt<float, float><<<dim3(4, 1), 256, 0, stream>>>(hFB, 512, cWh, 512, (const u16*)nullptr, ht0, 256, 32, 256, 512);
    k_gemm_nt<float, float><<<dim3(4, 1), 256, 0, stream>>>(hFB, 512, cWc, 512, (const u16*)nullptr, ct0, 256, 32, 256, 512);
    // 5. embed target + decoder y-part preactivations (bf16 out)
    k_embed<<<127 * 32, 256, 0, stream>>>(target, tgt_emb, Yemb, flag);
    k_gemm_nt<u16, u16><<<dim3(16, 64), 256, 0, stream>>>(Yemb, 256, cWih_d, 512, cb_d, Ypart, 1024, 4064, 1024, 256);
    // 6. persistent decoder v2 (fused attention pass, no cross-block sync)
    k_dec_persist<<<32, 512, 0, stream>>>(Ypart, cWhh_d, cWih_d, WattT, cWcomb, enc_p, ht0, ct0, hid);
    // 7. scores
    hipMemsetAsync(psum, 0, 4096 * sizeof(float), stream);
    k_lidx<<<(127 * 32 + 3) / 4, 256, 0, stream>>>(target, hid, Wvoc, lidx, flag);
    k_sumexp<<<dim3(250, 127), 256, 0, stream>>>(hid, Wvoc, psum, flag);
    k_scores<<<1, 64, 0, stream>>>(target, lidx, psum, d_out, flag);
}

// Round 14
// 14574.355 us; speedup vs baseline: 4.6968x; 4.6968x over previous
//
#include <hip/hip_runtime.h>
#include <hip/hip_bf16.h>
#include <math.h>

typedef unsigned int u32;
typedef unsigned short u16;

// ---------- bf16 helpers ----------
__device__ __forceinline__ float bfbits(u32 hi) { union { u32 u; float f; } v; v.u = hi; return v.f; }
__device__ __forceinline__ float lo16(u32 p) { return bfbits(p << 16); }
__device__ __forceinline__ float hi16(u32 p) { return bfbits(p & 0xffff0000u); }
__device__ __forceinline__ float b2f(u16 x) { return bfbits(((u32)x) << 16); }
__device__ __forceinline__ u16 f2b(float f) {
    union { float f; u32 u; } v; v.f = f;
    u32 u = v.u;
    u32 r = (u + 0x7fffu + ((u >> 16) & 1u)) >> 16;  // RNE
    return (u16)r;
}
__device__ __forceinline__ float cvtf(float x) { return x; }
__device__ __forceinline__ float cvtf(u16 x) { return b2f(x); }
__device__ __forceinline__ void storef(float* p, float v) { *p = v; }
__device__ __forceinline__ void storef(u16* p, float v) { *p = f2b(v); }
__device__ __forceinline__ float sigf(float x) { return 1.f / (1.f + expf(-x)); }
// dot of one uint4 (8 packed bf16) against 8 floats at p (LDS)
__device__ __forceinline__ float dotq(uint4 q, const float* p) {
    float4 a = *(const float4*)p;
    float4 b = *(const float4*)(p + 4);
    return lo16(q.x) * a.x + hi16(q.x) * a.y + lo16(q.y) * a.z + hi16(q.y) * a.w
         + lo16(q.z) * b.x + hi16(q.z) * b.y + lo16(q.w) * b.z + hi16(q.w) * b.w;
}
// 8-lane group reduce (lanes differing in bits 0..2)
__device__ __forceinline__ float red8(float a) {
    a += __shfl_xor(a, 1);
    a += __shfl_xor(a, 2);
    a += __shfl_xor(a, 4);
    return a;
}

// ---------- dtype-world detector (proven) ----------
__global__ void k_detect(const void* __restrict__ emb, int* __restrict__ flag) {
    __shared__ int s;
    if (threadIdx.x == 0) s = 0;
    __syncthreads();
    const u16* p = (const u16*)emb;
    int bad = 0;
    for (int i = threadIdx.x; i < 8192; i += 256) {
        float v = b2f(p[i]);
        if (!(fabsf(v) < 1e4f)) bad = 1;
    }
    if (bad) s = 1;
    __syncthreads();
    if (threadIdx.x == 0) *flag = s;
}

// ---------- weight canonicalizer ----------
__global__ void k_conv(const void* __restrict__ src, u16* __restrict__ dst, int n,
                       const int* __restrict__ flag) {
    int i = blockIdx.x * 256 + threadIdx.x;
    if (i >= n) return;
    if (*flag) dst[i] = f2b(((const float*)src)[i]);
    else       dst[i] = ((const u16*)src)[i];
}

// ---------- Watt transpose ----------
__global__ void k_wattT(const void* __restrict__ src, u16* __restrict__ dst,
                        const int* __restrict__ flag) {
    int c = blockIdx.x;   // 0..511
    int r = threadIdx.x;  // 0..255
    u16 v;
    if (*flag) v = f2b(((const float*)src)[(size_t)r * 512 + c]);
    else       v = ((const u16*)src)[(size_t)r * 512 + c];
    dst[(size_t)c * 256 + r] = v;
}

// ---------- embedding gather -> internal bf16 ----------
__global__ void k_embed(const int* __restrict__ tok, const void* __restrict__ emb,
                        u16* __restrict__ out, const int* __restrict__ flag) {
    int row = blockIdx.x;
    int e = threadIdx.x;
    int v = tok[row];
    u16 r;
    if (*flag) r = f2b(((const float*)emb)[(size_t)v * 256 + e]);
    else       r = ((const u16*)emb)[(size_t)v * 256 + e];
    out[(size_t)row * 256 + e] = r;
}

// ---------- generic GEMM: C[m][n] = sum_k A[m][k]*B[n][k] (+bias[n]) ----------
template <typename TA, typename TC>
__global__ __launch_bounds__(256) void k_gemm_nt(
    const TA* __restrict__ A, int lda,
    const u16* __restrict__ B, int ldb,
    const u16* __restrict__ bias,
    TC* __restrict__ C, int ldc,
    int M, int N, int K) {
    __shared__ float As[32][68];
    __shared__ float Bs[32][68];
    const int bm = blockIdx.y * 64, bn = blockIdx.x * 64;
    const int tid = threadIdx.x;
    const int tm = (tid & 15) * 4, tn = (tid >> 4) * 4;
    float acc[4][4] = {};
    const int ml = tid >> 2, kl = (tid & 3) * 8;
    for (int k0 = 0; k0 < K; k0 += 32) {
        {
            float v[8];
            if (bm + ml < M) {
                const TA* ap = A + (size_t)(bm + ml) * lda + (k0 + kl);
#pragma unroll
                for (int i = 0; i < 8; i++) v[i] = cvtf(ap[i]);
            } else {
#pragma unroll
                for (int i = 0; i < 8; i++) v[i] = 0.f;
            }
#pragma unroll
            for (int i = 0; i < 8; i++) As[kl + i][ml] = v[i];
        }
        {
            float v[8];
            if (bn + ml < N) {
                const u16* bp = B + (size_t)(bn + ml) * ldb + (k0 + kl);
#pragma unroll
                for (int i = 0; i < 8; i++) v[i] = b2f(bp[i]);
            } else {
#pragma unroll
                for (int i = 0; i < 8; i++) v[i] = 0.f;
            }
#pragma unroll
            for (int i = 0; i < 8; i++) Bs[kl + i][ml] = v[i];
        }
        __syncthreads();
#pragma unroll
        for (int k = 0; k < 32; k++) {
            float4 av = *(const float4*)&As[k][tm];
            float4 bv = *(const float4*)&Bs[k][tn];
            acc[0][0] += av.x * bv.x; acc[0][1] += av.x * bv.y; acc[0][2] += av.x * bv.z; acc[0][3] += av.x * bv.w;
            acc[1][0] += av.y * bv.x; acc[1][1] += av.y * bv.y; acc[1][2] += av.y * bv.z; acc[1][3] += av.y * bv.w;
            acc[2][0] += av.z * bv.x; acc[2][1] += av.z * bv.y; acc[2][2] += av.z * bv.z; acc[2][3] += av.z * bv.w;
            acc[3][0] += av.w * bv.x; acc[3][1] += av.w * bv.y; acc[3][2] += av.w * bv.z; acc[3][3] += av.w * bv.w;
        }
        __syncthreads();
    }
#pragma unroll
    for (int i = 0; i < 4; i++) {
        int m = bm + tm + i;
        if (m >= M) continue;
#pragma unroll
        for (int j = 0; j < 4; j++) {
            int n = bn + tn + j;
            float v = acc[i][j];
            if (bias) v += b2f(bias[n]);
            storef(&C[(size_t)m * ldc + n], v);
        }
    }
}

// ---------- persistent encoder v2: 64 blocks (dir*32+b) x 512 thr, 512 steps ----------
// 8-lane-per-row gate rows (independent loads, high MLP); gall in LDS.
__global__ __launch_bounds__(512) void k_enc_persist(
    const u16* __restrict__ Xf, const u16* __restrict__ Xb,
    const u16* __restrict__ Whh_f, const u16* __restrict__ Whh_b,
    u16* __restrict__ enc, float* __restrict__ hFB) {
    const int d = blockIdx.x >> 5, b = blockIdx.x & 31;
    const int j = threadIdx.x;
    const int q = j & 7, r8i = j >> 3;
    const u16* W = d ? Whh_b : Whh_f;
    __shared__ float hs[256];
    __shared__ float gall[1024];
    float c = 0.f;
    if (j < 256) hs[j] = 0.f;
    __syncthreads();
    const u16* Xd = d ? Xb : Xf;
    for (int step = 0; step < 512; step++) {
        const int pos = d ? (511 - step) : step;
        const u16* xp = Xd + ((size_t)pos * 32 + b) * 1024;
#pragma unroll 8
        for (int it = 0; it < 16; it++) {
            int row = it * 64 + r8i;
            const uint4* wh = (const uint4*)(W + (size_t)row * 256);
            float a = 0.f;
#pragma unroll
            for (int i = 0; i < 4; i++) {
                int u = q + 8 * i;
                a += dotq(wh[u], &hs[u * 8]);
            }
            a = red8(a);
            if (q == 0) gall[row] = a + b2f(xp[row]);
        }
        __syncthreads();
        if (j < 256) {
            float ig = sigf(gall[j]), fg = sigf(gall[256 + j]);
            float gg = tanhf(gall[512 + j]), og = sigf(gall[768 + j]);
            c = fg * c + ig * gg;
            float h = og * tanhf(c);
            hs[j] = h;
            enc[((size_t)b * 512 + pos) * 512 + (size_t)d * 256 + j] = f2b(h);
        }
        __syncthreads();
    }
    if (j < 256) hFB[(size_t)b * 512 + (size_t)d * 256 + j] = hs[j];
}

// ---------- persistent decoder v3: 32 blocks (batch) x 512 thr, 127 steps ----------
// All phases use independent-load patterns (no serial reduce chains):
// A gates(8-lane rows) -> update -> B g=WattT.h -> C1 e->ev (8-lane rows)
// -> C2 ctx accumulate (1 load + 8 FMA per row, unroll 8) -> E combine.
__global__ __launch_bounds__(512) void k_dec_persist(
    const u16* __restrict__ Ypart,
    const u16* __restrict__ Whh_d, const u16* __restrict__ Wih_d,
    const u16* __restrict__ WattT, const u16* __restrict__ Wcomb,
    const u16* __restrict__ enc,
    const float* __restrict__ ht0, const float* __restrict__ ct0,
    float* __restrict__ hid) {
    const int b = blockIdx.x;
    const int j = threadIdx.x;
    const int q = j & 7, r8i = j >> 3;   // 8 lanes per row
    const int wv = j >> 6, ln = j & 63;  // wave / lane
    __shared__ float hs[256], os[256];
    __shared__ float gall[1024];
    __shared__ float g[512], ev[512];
    __shared__ float pctxw[8][520];
    __shared__ float hc[768];
    __shared__ float redw[8];
    float c = 0.f;
    if (j < 256) {
        hs[j] = ht0[(size_t)b * 256 + j];
        c = ct0[(size_t)b * 256 + j];
        os[j] = 0.f;
    }
    __syncthreads();
    const uint4* encb = (const uint4*)(enc + (size_t)b * 512 * 512);
    for (int s = 0; s < 127; s++) {
        const u16* yp = Ypart + ((size_t)s * 32 + b) * 1024;
        // ---- A: 1024 gate rows, 8 lanes/row, 8 indep loads/row ----
#pragma unroll 4
        for (int it = 0; it < 16; it++) {
            int row = it * 64 + r8i;
            const uint4* wh = (const uint4*)(Whh_d + (size_t)row * 256);
            const uint4* wo = (const uint4*)(Wih_d + (size_t)row * 512 + 256);
            float a = 0.f;
#pragma unroll
            for (int i = 0; i < 4; i++) {
                int u = q + 8 * i;
                a += dotq(wh[u], &hs[u * 8]);
                a += dotq(wo[u], &os[u * 8]);
            }
            a = red8(a);
            if (q == 0) gall[row] = a + b2f(yp[row]);
        }
        __syncthreads();
        // ---- h/c update ----
        if (j < 256) {
            float ig = sigf(gall[j]), fg = sigf(gall[256 + j]);
            float gg = tanhf(gall[512 + j]), og = sigf(gall[768 + j]);
            c = fg * c + ig * gg;
            hs[j] = og * tanhf(c);
        }
        __syncthreads();
        // ---- B: g = WattT . h (512 rows) ----
#pragma unroll 4
        for (int it = 0; it < 8; it++) {
            int row = it * 64 + r8i;
            const uint4* wt = (const uint4*)(WattT + (size_t)row * 256);
            float a = 0.f;
#pragma unroll
            for (int i = 0; i < 4; i++) {
                int u = q + 8 * i;
                a += dotq(wt[u], &hs[u * 8]);
            }
            a = red8(a);
            if (q == 0) g[row] = a;
        }
        __syncthreads();
        // ---- C1: e[row] = enc[row].g -> ev = exp(e) (8-lane rows) ----
#pragma unroll 2
        for (int it = 0; it < 8; it++) {
            int row = it * 64 + r8i;
            const uint4* er = encb + (size_t)row * 64;
            float a = 0.f;
#pragma unroll
            for (int i = 0; i < 8; i++) {
                int u = q + 8 * i;
                a += dotq(er[u], &g[u * 8]);
            }
            a = red8(a);
            if (q == 0) ev[row] = expf(a);
        }
        __syncthreads();
        // ---- per-wave exp-sum + C2: ctx accumulation (independent rows) ----
        {
            float v = ev[wv * 64 + ln];
            for (int off = 32; off; off >>= 1) v += __shfl_down(v, off);
            if (ln == 0) redw[wv] = v;
        }
        {
            float a0 = 0, a1 = 0, a2 = 0, a3 = 0, a4 = 0, a5 = 0, a6 = 0, a7 = 0;
#pragma unroll 8
            for (int rr = 0; rr < 64; rr++) {
                int srow = wv * 64 + rr;
                uint4 qd = encb[(size_t)srow * 64 + ln];
                float w = ev[srow];
                a0 += w * lo16(qd.x); a1 += w * hi16(qd.x);
                a2 += w * lo16(qd.y); a3 += w * hi16(qd.y);
                a4 += w * lo16(qd.z); a5 += w * hi16(qd.z);
                a6 += w * lo16(qd.w); a7 += w * hi16(qd.w);
            }
            float* pw = &pctxw[wv][ln * 8];
            pw[0] = a0; pw[1] = a1; pw[2] = a2; pw[3] = a3;
            pw[4] = a4; pw[5] = a5; pw[6] = a6; pw[7] = a7;
        }
        __syncthreads();
        // ---- reduce ctx over waves, build [h;ctx] ----
        {
            float cxv = 0.f;
#pragma unroll
            for (int w = 0; w < 8; w++) cxv += pctxw[w][j];
            float inv = 1.f / (redw[0] + redw[1] + redw[2] + redw[3] +
                               redw[4] + redw[5] + redw[6] + redw[7]);
            hc[256 + j] = cxv * inv;
            if (j < 256) hc[j] = hs[j];
        }
        __syncthreads();
        // ---- E: o_t = tanh(Wcomb [h;ctx]) (256 rows, 8 lanes/row) ----
#pragma unroll 2
        for (int it = 0; it < 4; it++) {
            int row = it * 64 + r8i;
            const uint4* wc = (const uint4*)(Wcomb + (size_t)row * 768);
            float a = 0.f;
#pragma unroll
            for (int i = 0; i < 12; i++) {
                int u = q + 8 * i;
                a += dotq(wc[u], &hc[u * 8]);
            }
            a = red8(a);
            if (q == 0) {
                float o = tanhf(a);
                os[row] = o;
                hid[((size_t)s * 32 + b) * 256 + row] = o;
            }
        }
        __syncthreads();
    }
}

// ---------- logit at target index ----------
__global__ __launch_bounds__(256) void k_lidx(
    const int* __restrict__ target, const float* __restrict__ hid,
    const void* __restrict__ WvocV, float* __restrict__ lidx,
    const int* __restrict__ flag) {
    int p = blockIdx.x * 4 + (threadIdx.x >> 6);
    if (p >= 127 * 32) return;
    int lane = threadIdx.x & 63;
    int t = p >> 5, b = p & 31;
    int idx = target[(t + 1) * 32 + b];
    const float* h = hid + (size_t)p * 256;
    const bool f32w = (*flag != 0);
    float a = 0.f;
#pragma unroll
    for (int i = 0; i < 4; i++) {
        int k = lane * 4 + i;
        float wv = f32w ? ((const float*)WvocV)[(size_t)idx * 256 + k]
                        : b2f(((const u16*)WvocV)[(size_t)idx * 256 + k]);
        a += h[k] * wv;
    }
    for (int off = 32; off; off >>= 1) a += __shfl_down(a, off);
    if (lane == 0) lidx[p] = a;
}

// ---------- fused vocab GEMM + sum(exp(logit)) ----------
__global__ __launch_bounds__(256) void k_sumexp(
    const float* __restrict__ hid, const void* __restrict__ WvocV,
    float* __restrict__ psum, const int* __restrict__ flag) {
    const int t = blockIdx.y;
    const int cb = blockIdx.x * 128;
    const int tid = threadIdx.x;
    const bool f32w = (*flag != 0);
    __shared__ float Hsh[32][260];
    __shared__ float Wsh[32][132];
    __shared__ float red[32][33];
    {
        int r = tid >> 3, kb = (tid & 7) * 32;
        const float4* hp4 = (const float4*)(hid + ((size_t)t * 32 + r) * 256 + kb);
        float4* dst = (float4*)&Hsh[r][kb];
#pragma unroll
        for (int i = 0; i < 8; i++) dst[i] = hp4[i];
    }
    const int rt = tid >> 5, ct = tid & 31;
    float acc[4][4] = {};
    for (int kc = 0; kc < 8; kc++) {
        __syncthreads();
        {
            int c = tid >> 1, half = tid & 1;
            int k0 = half * 16;
            float w[16];
            if (f32w) {
                const float4* wf = (const float4*)((const float*)WvocV + (size_t)(cb + c) * 256 + kc * 32 + half * 16);
                float4 a0 = wf[0], a1 = wf[1], a2 = wf[2], a3 = wf[3];
                w[0] = a0.x; w[1] = a0.y; w[2] = a0.z; w[3] = a0.w;
                w[4] = a1.x; w[5] = a1.y; w[6] = a1.z; w[7] = a1.w;
                w[8] = a2.x; w[9] = a2.y; w[10] = a2.z; w[11] = a2.w;
                w[12] = a3.x; w[13] = a3.y; w[14] = a3.z; w[15] = a3.w;
            } else {
                const uint4* w4 = (const uint4*)((const u16*)WvocV + (size_t)(cb + c) * 256 + kc * 32 + half * 16);
                uint4 q0 = w4[0], q1 = w4[1];
                w[0] = lo16(q0.x); w[1] = hi16(q0.x); w[2] = lo16(q0.y); w[3] = hi16(q0.y);
                w[4] = lo16(q0.z); w[5] = hi16(q0.z); w[6] = lo16(q0.w); w[7] = hi16(q0.w);
                w[8] = lo16(q1.x); w[9] = hi16(q1.x); w[10] = lo16(q1.y); w[11] = hi16(q1.y);
                w[12] = lo16(q1.z); w[13] = hi16(q1.z); w[14] = lo16(q1.w); w[15] = hi16(q1.w);
            }
#pragma unroll
            for (int i = 0; i < 16; i++) Wsh[k0 + i][c] = w[i];
        }
        __syncthreads();
#pragma unroll
        for (int k = 0; k < 32; k++) {
            float4 bv = *(const float4*)&Wsh[k][ct * 4];
            float a0 = Hsh[rt * 4 + 0][kc * 32 + k];
            float a1 = Hsh[rt * 4 + 1][kc * 32 + k];
            float a2 = Hsh[rt * 4 + 2][kc * 32 + k];
            float a3 = Hsh[rt * 4 + 3][kc * 32 + k];
            acc[0][0] += a0 * bv.x; acc[0][1] += a0 * bv.y; acc[0][2] += a0 * bv.z; acc[0][3] += a0 * bv.w;
            acc[1][0] += a1 * bv.x; acc[1][1] += a1 * bv.y; acc[1][2] += a1 * bv.z; acc[1][3] += a1 * bv.w;
            acc[2][0] += a2 * bv.x; acc[2][1] += a2 * bv.y; acc[2][2] += a2 * bv.z; acc[2][3] += a2 * bv.w;
            acc[3][0] += a3 * bv.x; acc[3][1] += a3 * bv.y; acc[3][2] += a3 * bv.z; acc[3][3] += a3 * bv.w;
        }
    }
#pragma unroll
    for (int i = 0; i < 4; i++) {
        float s = expf(acc[i][0]) + expf(acc[i][1]) + expf(acc[i][2]) + expf(acc[i][3]);
        red[rt * 4 + i][ct] = s;
    }
    __syncthreads();
    if (tid < 32) {
        float s = 0.f;
#pragma unroll 8
        for (int c = 0; c < 32; c++) s += red[tid][c];
        atomicAdd(&psum[(size_t)t * 32 + tid], s);
    }
}

// ---------- final scores ----------
__global__ void k_scores(const int* __restrict__ target, const float* __restrict__ lidx,
                         const float* __restrict__ psum, void* __restrict__ outv,
                         const int* __restrict__ flag) {
    int b = threadIdx.x;
    if (b >= 32) return;
    float acc = 0.f;
    for (int t = 0; t < 127; t++) {
        int idx = target[(t + 1) * 32 + b];
        if (idx != 0) {
            int row = t * 32 + b;
            acc += lidx[row] - logf(psum[row]);
        }
    }
    if (*flag) ((float*)outv)[b] = acc;
    else       ((u16*)outv)[b] = f2b(acc);
}

extern "C" void kernel_launch(void* const* d_in, const int* in_sizes, int n_in,
                              void* d_out, int out_size, void* d_ws, size_t ws_size,
                              hipStream_t stream) {
    const int* source = (const int*)d_in[0];
    const int* target = (const int*)d_in[1];
    const void* src_emb = d_in[2];
    const void* tgt_emb = d_in[3];
    const void* Wih_f = d_in[4];
    const void* Whh_f = d_in[5];
    const void* b_f = d_in[6];
    const void* Wih_b = d_in[7];
    const void* Whh_b = d_in[8];
    const void* b_b = d_in[9];
    const void* Wih_d = d_in[10];
    const void* Whh_d = d_in[11];
    const void* b_d = d_in[12];
    const void* Wh = d_in[13];
    const void* Wc = d_in[14];
    const void* Watt = d_in[15];
    const void* Wcomb = d_in[16];
    const void* Wvoc = d_in[17];

    // ---- workspace layout: [flag pad][f32 buffers][u16 buffers] ----
    int* flag = (int*)d_ws;
    float* fw = (float*)d_ws;
    size_t off = 64;
    float* hid = fw + off;    off += (size_t)127 * 32 * 256;
    float* hFB = fw + off;    off += (size_t)32 * 512;
    float* ht0 = fw + off;    off += (size_t)32 * 256;
    float* ct0 = fw + off;    off += (size_t)32 * 256;
    float* lidx = fw + off;   off += 4096;
    float* psum = fw + off;   off += 4096;
    u16* ub = (u16*)(fw + off);
    size_t uo = 0;
    u16* X = ub + uo;       uo += (size_t)512 * 32 * 256;
    u16* Yemb = ub + uo;    uo += (size_t)127 * 32 * 256;
    u16* Xf = ub + uo;      uo += (size_t)512 * 32 * 1024;
    u16* Xb = ub + uo;      uo += (size_t)512 * 32 * 1024;
    u16* Ypart = ub + uo;   uo += (size_t)127 * 32 * 1024;
    u16* enc_p = ub + uo;   uo += (size_t)32 * 512 * 512;
    u16* WattT = ub + uo;   uo += 131072;
    u16* cWih_f = ub + uo;  uo += 262144;
    u16* cWhh_f = ub + uo;  uo += 262144;
    u16* cb_f = ub + uo;    uo += 1024;
    u16* cWih_b = ub + uo;  uo += 262144;
    u16* cWhh_b = ub + uo;  uo += 262144;
    u16* cb_b = ub + uo;    uo += 1024;
    u16* cWih_d = ub + uo;  uo += 524288;
    u16* cWhh_d = ub + uo;  uo += 262144;
    u16* cb_d = ub + uo;    uo += 1024;
    u16* cWh = ub + uo;     uo += 131072;
    u16* cWc = ub + uo;     uo += 131072;
    u16* cWcomb = ub + uo;  uo += 196608;
    size_t needed = off * 4 + uo * 2;
    if (ws_size < needed) return;

    // 0. detect dtype world, canonicalize weights
    k_detect<<<1, 256, 0, stream>>>(src_emb, flag);
    auto conv = [&](const void* s, u16* d, int n) {
        k_conv<<<(n + 255) / 256, 256, 0, stream>>>(s, d, n, flag);
    };
    conv(Wih_f, cWih_f, 262144);  conv(Whh_f, cWhh_f, 262144);  conv(b_f, cb_f, 1024);
    conv(Wih_b, cWih_b, 262144);  conv(Whh_b, cWhh_b, 262144);  conv(b_b, cb_b, 1024);
    conv(Wih_d, cWih_d, 524288);  conv(Whh_d, cWhh_d, 262144);  conv(b_d, cb_d, 1024);
    conv(Wh, cWh, 131072);        conv(Wc, cWc, 131072);
    conv(Wcomb, cWcomb, 196608);
    k_wattT<<<512, 256, 0, stream>>>(Watt, WattT, flag);

    // 1. embed source
    k_embed<<<512 * 32, 256, 0, stream>>>(source, src_emb, X, flag);
    // 2. x-part gate preactivations, both directions (bf16 out)
    k_gemm_nt<u16, u16><<<dim3(16, 256), 256, 0, stream>>>(X, 256, cWih_f, 256, cb_f, Xf, 1024, 16384, 1024, 256);
    k_gemm_nt<u16, u16><<<dim3(16, 256), 256, 0, stream>>>(X, 256, cWih_b, 256, cb_b, Xb, 1024, 16384, 1024, 256);
    // 3. persistent encoder v2
    k_enc_persist<<<64, 512, 0, stream>>>(Xf, Xb, cWhh_f, cWhh_b, enc_p, hFB);
    // 4. initial decoder state
    k_gemm_nt<float, float><<<dim3(4, 1), 256, 0, stream>>>(hFB, 512, cWh, 512, (const u16*)nullptr, ht0, 256, 32, 256, 512);
    k_gemm_nt<float, float><<<dim3(4, 1), 256, 0, stream>>>(hFB, 512, cWc, 512, (const u16*)nullptr, ct0, 256, 32, 256, 512);
    // 5. embed target + decoder y-part preactivations (bf16 out)
    k_embed<<<127 * 32, 256, 0, stream>>>(target, tgt_emb, Yemb, flag);
    k_gemm_nt<u16, u16><<<dim3(16, 64), 256, 0, stream>>>(Yemb, 256, cWih_d, 512, cb_d, Ypart, 1024, 4064, 1024, 256);
    // 6. persistent decoder v3 (ILP-friendly phases, no cross-block sync)
    k_dec_persist<<<32, 512, 0, stream>>>(Ypart, cWhh_d, cWih_d, WattT, cWcomb, enc_p, ht0, ct0, hid);
    // 7. scores
    hipMemsetAsync(psum, 0, 4096 * sizeof(float), stream);
    k_lidx<<<(127 * 32 + 3) / 4, 256, 0, stream>>>(target, hid, Wvoc, lidx, flag);
    k_sumexp<<<dim3(250, 127), 256, 0, stream>>>(hid, Wvoc, psum, flag);
    k_scores<<<1, 64, 0, stream>>>(target, lidx, psum, d_out, flag);
}